// Round 7
// baseline (969.887 us; speedup 1.0000x reference)
//
#include <hip/hip_runtime.h>

#define F_IN 512
#define HDIM 16
#define F_OUT 40
#define BTGT 64   // targets per bucket
#define REPL 8    // sub-regions per bucket == XCD partitions
#define NCH 512   // blocks for edge-chunked kernels (hist/bucket)
#define ECH 2048  // edges staged in LDS per chunk (8 KB)

typedef unsigned short ushortT;

__device__ __forceinline__ unsigned f2bf(float f) {  // RNE float->bf16 bits
  unsigned u = __float_as_uint(f);
  u += 0x7FFF + ((u >> 16) & 1);
  return u >> 16;
}
__device__ __forceinline__ float bf2f(ushortT b) {
  return __uint_as_float(((unsigned)b) << 16);
}
__device__ __forceinline__ float bf2f_lo(unsigned w) {
  return __uint_as_float(w << 16);
}
__device__ __forceinline__ float bf2f_hi(unsigned w) {
  return __uint_as_float(w & 0xFFFF0000u);
}

__device__ __forceinline__ int load_src(const void* ei, int is64, int e) {
  return is64 ? (int)((const unsigned int*)ei)[2 * (long long)e] : ((const int*)ei)[e];
}
__device__ __forceinline__ int load_dst(const void* ei, int is64, int e, int E) {
  long long i = (long long)E + e;
  return is64 ? (int)((const unsigned int*)ei)[2 * i] : ((const int*)ei)[i];
}

extern "C" __global__ void k_init(int* __restrict__ hist, int m, int* __restrict__ flag) {
  int i = blockIdx.x * blockDim.x + threadIdx.x;
  if (i < m) hist[i] = 0;
  if (i == 0) *flag = 1;
}

extern "C" __global__ void k_detect(const unsigned int* __restrict__ w, int npairs,
                                    int* __restrict__ flag) {
  int i = blockIdx.x * blockDim.x + threadIdx.x;
  if (i < npairs && w[2 * i + 1] != 0u) atomicAnd(flag, 0);
}

// Per-block LDS histogram of NBK bucket counters; replica = blockIdx&7.
// Edge->block chunking MUST match k_bucket.
extern "C" __global__ __launch_bounds__(256) void k_hist(const void* __restrict__ ei, int E,
                                                         int echunk, int* __restrict__ hist,
                                                         int NBK,
                                                         const int* __restrict__ flag) {
  extern __shared__ int lh[];
  int g = blockIdx.x, t = threadIdx.x;
  for (int i = t; i < NBK; i += 256) lh[i] = 0;
  __syncthreads();
  int is64 = *flag;
  int e0 = g * echunk;
  int e1 = e0 + echunk;
  if (e1 > E) e1 = E;
  if (e0 < e1) {
    if (is64 && ((E & 1) == 0)) {
      const int* w32 = (const int*)ei;
      int evend = e0 + ((e1 - e0) & ~1);
      for (int e = e0 + 2 * t; e + 1 < evend + 2; e += 512) {
        if (e + 1 >= e1) break;
        int4 d4 = *(const int4*)(w32 + 2 * ((size_t)E + e));
        atomicAdd(&lh[(unsigned)d4.x >> 6], 1);
        atomicAdd(&lh[(unsigned)d4.z >> 6], 1);
      }
      for (int e = evend + t; e < e1; e += 256)
        atomicAdd(&lh[(unsigned)load_dst(ei, 1, e, E) >> 6], 1);
    } else {
      for (int e = e0 + t; e < e1; e += 256)
        atomicAdd(&lh[(unsigned)load_dst(ei, is64, e, E) >> 6], 1);
    }
  }
  __syncthreads();
  int repl = g & (REPL - 1);
  for (int i = t; i < NBK; i += 256) {
    int v = lh[i];
    if (v) atomicAdd(&hist[i * REPL + repl], v);
  }
}

extern "C" __global__ __launch_bounds__(1024) void k_scanb(const int* __restrict__ hist,
                                                           int* __restrict__ boffs,
                                                           int* __restrict__ bcur, int M) {
  __shared__ int sh[1024];
  int tid = threadIdx.x;
  int C = (M + 1023) / 1024;
  int base = tid * C;
  int s = 0;
  for (int k = 0; k < C; k++) {
    int idx = base + k;
    if (idx < M) s += hist[idx];
  }
  sh[tid] = s;
  __syncthreads();
  for (int d = 1; d < 1024; d <<= 1) {
    int t2 = (tid >= d) ? sh[tid - d] : 0;
    __syncthreads();
    sh[tid] += t2;
    __syncthreads();
  }
  int run = sh[tid] - s;
  for (int k = 0; k < C; k++) {
    int idx = base + k;
    if (idx < M) {
      int v = hist[idx];
      boffs[idx] = run;
      bcur[idx] = run;
      run += v;
    }
  }
  if (tid == 1023) boffs[M] = run;  // == E
}

// scatter packed words src | (local_col<<20); same chunking as k_hist.
extern "C" __global__ __launch_bounds__(256) void k_bucket(const void* __restrict__ ei, int E,
                                                           int echunk, int* __restrict__ bcur,
                                                           unsigned int* __restrict__ bked,
                                                           const int* __restrict__ flag) {
  int g = blockIdx.x, t = threadIdx.x;
  int is64 = *flag;
  int repl = g & (REPL - 1);
  int e0 = g * echunk;
  int e1 = e0 + echunk;
  if (e1 > E) e1 = E;
  if (e0 >= e1) return;
  if (is64 && ((E & 1) == 0)) {
    const int* w32 = (const int*)ei;
    int evend = e0 + ((e1 - e0) & ~1);
    for (int e = e0 + 2 * t; e + 1 < evend + 2; e += 512) {
      if (e + 1 >= e1) break;
      int4 s4 = *(const int4*)(w32 + 2 * (size_t)e);
      int4 d4 = *(const int4*)(w32 + 2 * ((size_t)E + e));
      {
        int idx = ((unsigned)d4.x >> 6) * REPL + repl;
        int p = atomicAdd(&bcur[idx], 1);
        __builtin_nontemporal_store(
            (unsigned)s4.x | ((unsigned)(d4.x & (BTGT - 1)) << 20), &bked[p]);
      }
      {
        int idx = ((unsigned)d4.z >> 6) * REPL + repl;
        int p = atomicAdd(&bcur[idx], 1);
        __builtin_nontemporal_store(
            (unsigned)s4.z | ((unsigned)(d4.z & (BTGT - 1)) << 20), &bked[p]);
      }
    }
    for (int e = evend + t; e < e1; e += 256) {
      int r = load_src(ei, 1, e);
      int c = load_dst(ei, 1, e, E);
      int idx = ((unsigned)c >> 6) * REPL + repl;
      int p = atomicAdd(&bcur[idx], 1);
      __builtin_nontemporal_store(
          (unsigned)r | ((unsigned)(c & (BTGT - 1)) << 20), &bked[p]);
    }
  } else {
    for (int e = e0 + t; e < e1; e += 256) {
      int r = load_src(ei, is64, e);
      int c = load_dst(ei, is64, e, E);
      int idx = ((unsigned)c >> 6) * REPL + repl;
      int p = atomicAdd(&bcur[idx], 1);
      __builtin_nontemporal_store(
          (unsigned)r | ((unsigned)(c & (BTGT - 1)) << 20), &bked[p]);
    }
  }
}

// per-bucket local degree count (LDS-staged edges) -> dis = rsqrt(deg+1)
extern "C" __global__ __launch_bounds__(256, 2) void k_degb(
    const unsigned int* __restrict__ bked, const int* __restrict__ boffs,
    float* __restrict__ dis, int n) {
  __shared__ int lc[BTGT];
  __shared__ unsigned ebd[ECH];
  int b = blockIdx.x, t = threadIdx.x;
  if (t < BTGT) lc[t] = 0;
  __syncthreads();
  int beg = boffs[b * REPL], end = boffs[(b + 1) * REPL];
  for (int cbeg = beg; cbeg < end; cbeg += ECH) {
    int len = end - cbeg;
    if (len > ECH) len = ECH;
    for (int i = t; i < len; i += 256) ebd[i] = bked[cbeg + i];
    __syncthreads();
    for (int i = t; i < len; i += 256) atomicAdd(&lc[ebd[i] >> 20], 1);
    __syncthreads();
  }
  if (t < BTGT) {
    int i = b * BTGT + t;
    if (i < n) dis[i] = rsqrtf((float)lc[t] + 1.0f);
  }
}

// hs(bf16) = dis .* (x @ W1). Block=256 rows, LDS-staged swizzled x tile.
extern "C" __global__ __launch_bounds__(256) void k_mm1s(
    const float* __restrict__ x, const float* __restrict__ W1, const float* __restrict__ dis,
    ushortT* __restrict__ hs, int n) {
  __shared__ float xs[256 * 32];
  __shared__ float w1s[F_IN * HDIM];
  int t = threadIdx.x;
  int row0 = blockIdx.x * 256;
  {
    const float4* wg = (const float4*)W1;
    float4* wl = (float4*)w1s;
    for (int i = t; i < F_IN * HDIM / 4; i += 256) wl[i] = wg[i];
  }
  int r = row0 + t;
  bool active = (r < n);
  bool fullblk = (row0 + 255 < n);
  float acc[HDIM];
#pragma unroll
  for (int j = 0; j < HDIM; j++) acc[j] = 0.f;

  float4* xs4 = (float4*)xs;
  for (int kc = 0; kc < F_IN / 32; kc++) {
    __syncthreads();
    if (fullblk) {
#pragma unroll
      for (int it = 0; it < 8; it++) {
        int f = it * 256 + t;
        int r2 = f >> 3, fi = f & 7;
        float4 v = ((const float4*)(x + (size_t)(row0 + r2) * F_IN + kc * 32))[fi];
        xs4[r2 * 8 + (fi ^ (r2 & 7))] = v;
      }
    } else {
      for (int it = 0; it < 8; it++) {
        int f = it * 256 + t;
        int r2 = f >> 3, fi = f & 7;
        float4 v = make_float4(0.f, 0.f, 0.f, 0.f);
        if (row0 + r2 < n)
          v = ((const float4*)(x + (size_t)(row0 + r2) * F_IN + kc * 32))[fi];
        xs4[r2 * 8 + (fi ^ (r2 & 7))] = v;
      }
    }
    __syncthreads();
    if (active) {
#pragma unroll
      for (int i = 0; i < 8; i++) {
        int ii = i ^ (t & 7);
        float4 xv = xs4[t * 8 + ii];
        float xk[4] = {xv.x, xv.y, xv.z, xv.w};
        int kb = kc * 32 + i * 4;
#pragma unroll
        for (int kk = 0; kk < 4; kk++) {
          const float4* wr = (const float4*)(w1s + (size_t)(kb + kk) * HDIM);
#pragma unroll
          for (int q = 0; q < HDIM / 4; q++) {
            float4 wv = wr[q];
            acc[4 * q + 0] = fmaf(xk[kk], wv.x, acc[4 * q + 0]);
            acc[4 * q + 1] = fmaf(xk[kk], wv.y, acc[4 * q + 1]);
            acc[4 * q + 2] = fmaf(xk[kk], wv.z, acc[4 * q + 2]);
            acc[4 * q + 3] = fmaf(xk[kk], wv.w, acc[4 * q + 3]);
          }
        }
      }
    }
  }
  if (active) {
    float d = dis[r];
    unsigned wds[8];
#pragma unroll
    for (int q = 0; q < 8; q++) {
      unsigned lo = f2bf(d * acc[2 * q]);
      unsigned hi = f2bf(d * acc[2 * q + 1]);
      wds[q] = lo | (hi << 16);
    }
    uint4* o = (uint4*)(hs + (size_t)r * HDIM);
    o[0] = make_uint4(wds[0], wds[1], wds[2], wds[3]);
    o[1] = make_uint4(wds[4], wds[5], wds[6], wds[7]);
  }
}

// Shared gather+accumulate body: bucket edges staged in LDS, 8 lanes/edge,
// uint (2xbf16) gathers, ILP-8 across stripes of 256 edges.
__device__ __forceinline__ void agg_body(const ushortT* __restrict__ feat,
                                         const unsigned int* __restrict__ bked,
                                         unsigned* __restrict__ eb,
                                         float* __restrict__ acc, int beg, int end, int t) {
  int g = t >> 3, j2 = t & 7;
  for (int cbeg = beg; cbeg < end; cbeg += ECH) {
    int len = end - cbeg;
    if (len > ECH) len = ECH;
    for (int i = t; i < len; i += 256) eb[i] = bked[cbeg + i];
    __syncthreads();
    int nf = len >> 8;
    for (int s = 0; s < nf; s++) {
      int base = (s << 8) + (g << 3);
      unsigned u[8];
#pragma unroll
      for (int k = 0; k < 8; k++) u[k] = eb[base + k];
      unsigned w[8];
#pragma unroll
      for (int k = 0; k < 8; k++)
        w[k] = *(const unsigned*)(feat + ((size_t)(u[k] & 0xFFFFFu) << 4) + (j2 << 1));
#pragma unroll
      for (int k = 0; k < 8; k++) {
        int a = ((u[k] >> 20) << 4) + (j2 << 1);
        atomicAdd(&acc[a], bf2f_lo(w[k]));
        atomicAdd(&acc[a + 1], bf2f_hi(w[k]));
      }
    }
    for (int i = (nf << 8) + g; i < len; i += 32) {
      unsigned u = eb[i];
      unsigned w = *(const unsigned*)(feat + ((size_t)(u & 0xFFFFFu) << 4) + (j2 << 1));
      int a = ((u >> 20) << 4) + (j2 << 1);
      atomicAdd(&acc[a], bf2f_lo(w));
      atomicAdd(&acc[a + 1], bf2f_hi(w));
    }
    __syncthreads();
  }
}

// layer-1 aggregate: zs(bf16) = dis * relu( di*(sum_nb hs[s] + hs[i]) + b1 )
extern "C" __global__ __launch_bounds__(256, 2) void k_agg1(
    const ushortT* __restrict__ hs, const unsigned int* __restrict__ bked,
    const int* __restrict__ boffs, const float* __restrict__ dis,
    const float* __restrict__ b1, ushortT* __restrict__ zs, int n) {
  __shared__ float acc[BTGT * HDIM];
  __shared__ unsigned eb[ECH];
  int b = blockIdx.x, t = threadIdx.x;
  for (int k = t; k < BTGT * HDIM; k += 256) acc[k] = 0.f;
  __syncthreads();
  int beg = boffs[b * REPL], end = boffs[(b + 1) * REPL];
  agg_body(hs, bked, eb, acc, beg, end, t);
  int g = t >> 4, j = t & 15;
  for (int il = g; il < BTGT; il += 16) {
    int i = b * BTGT + il;
    if (i < n) {
      float di = dis[i];
      float v = di * (acc[il * HDIM + j] + bf2f(hs[(size_t)i * HDIM + j])) + b1[j];
      v = fmaxf(v, 0.f);
      zs[(size_t)i * HDIM + j] = (ushortT)f2bf(di * v);
    }
  }
}

// layer-2 aggregate fused with mm2: out = (di*(sum_nb zs[s] + zs[i])) @ W2 + b2
extern "C" __global__ __launch_bounds__(256, 2) void k_agg2f(
    const ushortT* __restrict__ zs, const unsigned int* __restrict__ bked,
    const int* __restrict__ boffs, const float* __restrict__ dis,
    const float* __restrict__ W2, const float* __restrict__ b2, float* __restrict__ out,
    int n) {
  __shared__ float acc[BTGT * HDIM];
  __shared__ unsigned eb[ECH];
  __shared__ float w2s[HDIM * F_OUT];
  __shared__ float b2s[F_OUT];
  int b = blockIdx.x, t = threadIdx.x;
  for (int k = t; k < BTGT * HDIM; k += 256) acc[k] = 0.f;
  for (int k = t; k < HDIM * F_OUT; k += 256) w2s[k] = W2[k];
  if (t < F_OUT) b2s[t] = b2[t];
  __syncthreads();
  int beg = boffs[b * REPL], end = boffs[(b + 1) * REPL];
  agg_body(zs, bked, eb, acc, beg, end, t);
  int g = t >> 4, j = t & 15;
  for (int il = g; il < BTGT; il += 16) {
    int i = b * BTGT + il;
    if (i < n) {
      float di = dis[i];
      acc[il * HDIM + j] = di * (acc[il * HDIM + j] + bf2f(zs[(size_t)i * HDIM + j]));
    }
  }
  __syncthreads();
  int il = t >> 2, qo = t & 3;
  int i = b * BTGT + il;
  if (i < n) {
    float tv[HDIM];
#pragma unroll
    for (int k = 0; k < HDIM; k++) tv[k] = acc[il * HDIM + k];
#pragma unroll
    for (int jj = 0; jj < 10; jj++) {
      int col = qo * 10 + jj;
      float s = b2s[col];
#pragma unroll
      for (int k = 0; k < HDIM; k++) s = fmaf(tv[k], w2s[k * F_OUT + col], s);
      out[(size_t)i * F_OUT + col] = s;
    }
  }
}

extern "C" void kernel_launch(void* const* d_in, const int* in_sizes, int n_in,
                              void* d_out, int out_size, void* d_ws, size_t ws_size,
                              hipStream_t stream) {
  const float* x = (const float*)d_in[0];
  const void* ei = d_in[1];
  const float* W1 = (const float*)d_in[2];
  const float* b1 = (const float*)d_in[3];
  const float* W2 = (const float*)d_in[4];
  const float* b2 = (const float*)d_in[5];
  float* out = (float*)d_out;

  const int n = in_sizes[0] / F_IN;  // 100000
  const int E = in_sizes[1] / 2;     // 3200000
  const int NBK = (n + BTGT - 1) / BTGT;  // 1563
  const int M = NBK * REPL;               // 12504
  int echunk = (E + NCH - 1) / NCH;
  echunk = (echunk + 1) & ~1;  // even so int4 paths stay aligned

  char* w = (char*)d_ws;
  auto alloc = [&](size_t bytes) {
    char* p = w;
    w += (bytes + 255) & ~(size_t)255;
    return p;
  };
  int* flag = (int*)alloc(4);
  int* hist = (int*)alloc((size_t)M * 4);
  int* boffs = (int*)alloc((size_t)(M + 1) * 4);
  int* bcur = (int*)alloc((size_t)M * 4);
  float* dis = (float*)alloc((size_t)n * 4);
  unsigned int* bked = (unsigned int*)alloc((size_t)E * 4);
  ushortT* hs = (ushortT*)alloc((size_t)n * HDIM * 2);
  ushortT* zs = (ushortT*)alloc((size_t)n * HDIM * 2);

  dim3 B(256);
  hipLaunchKernelGGL(k_init, dim3((M + 255) / 256), B, 0, stream, hist, M, flag);
  int npairs = 4096;
  if (npairs > E) npairs = E;
  hipLaunchKernelGGL(k_detect, dim3((npairs + 255) / 256), B, 0, stream,
                     (const unsigned int*)ei, npairs, flag);
  hipLaunchKernelGGL(k_hist, dim3(NCH), B, (size_t)NBK * 4, stream, ei, E, echunk, hist, NBK,
                     flag);
  hipLaunchKernelGGL(k_scanb, dim3(1), dim3(1024), 0, stream, hist, boffs, bcur, M);
  hipLaunchKernelGGL(k_bucket, dim3(NCH), B, 0, stream, ei, E, echunk, bcur, bked, flag);
  hipLaunchKernelGGL(k_degb, dim3(NBK), B, 0, stream, bked, boffs, dis, n);
  hipLaunchKernelGGL(k_mm1s, dim3((n + 255) / 256), B, 0, stream, x, W1, dis, hs, n);
  hipLaunchKernelGGL(k_agg1, dim3(NBK), B, 0, stream, hs, bked, boffs, dis, b1, zs, n);
  hipLaunchKernelGGL(k_agg2f, dim3(NBK), B, 0, stream, zs, bked, boffs, dis, W2, b2, out, n);
}

// Round 8
// 957.220 us; speedup vs baseline: 1.0132x; 1.0132x over previous
//
#include <hip/hip_runtime.h>

#define F_IN 512
#define HDIM 16
#define F_OUT 40
#define BTGT 64   // targets per bucket
#define REPL 8    // sub-regions per bucket == XCD partitions
#define NCH 512   // blocks for edge-chunked kernels (hist/bucket)

typedef unsigned short ushortT;

__device__ __forceinline__ unsigned f2bf(float f) {  // RNE float->bf16 bits
  unsigned u = __float_as_uint(f);
  u += 0x7FFF + ((u >> 16) & 1);
  return u >> 16;
}
__device__ __forceinline__ float bf2f(ushortT b) {
  return __uint_as_float(((unsigned)b) << 16);
}
__device__ __forceinline__ float bf2f_lo(unsigned w) {
  return __uint_as_float(w << 16);
}
__device__ __forceinline__ float bf2f_hi(unsigned w) {
  return __uint_as_float(w & 0xFFFF0000u);
}

__device__ __forceinline__ int load_src(const void* ei, int is64, int e) {
  return is64 ? (int)((const unsigned int*)ei)[2 * (long long)e] : ((const int*)ei)[e];
}
__device__ __forceinline__ int load_dst(const void* ei, int is64, int e, int E) {
  long long i = (long long)E + e;
  return is64 ? (int)((const unsigned int*)ei)[2 * i] : ((const int*)ei)[i];
}

extern "C" __global__ void k_init(int* __restrict__ hist, int m, int* __restrict__ flag) {
  int i = blockIdx.x * blockDim.x + threadIdx.x;
  if (i < m) hist[i] = 0;
  if (i == 0) *flag = 1;
}

extern "C" __global__ void k_detect(const unsigned int* __restrict__ w, int npairs,
                                    int* __restrict__ flag) {
  int i = blockIdx.x * blockDim.x + threadIdx.x;
  if (i < npairs && w[2 * i + 1] != 0u) atomicAnd(flag, 0);
}

// Per-block LDS histogram of NBK bucket counters; replica = blockIdx&7.
// Edge->block chunking MUST match k_bucket.
extern "C" __global__ __launch_bounds__(256) void k_hist(const void* __restrict__ ei, int E,
                                                         int echunk, int* __restrict__ hist,
                                                         int NBK,
                                                         const int* __restrict__ flag) {
  extern __shared__ int lh[];
  int g = blockIdx.x, t = threadIdx.x;
  for (int i = t; i < NBK; i += 256) lh[i] = 0;
  __syncthreads();
  int is64 = *flag;
  int e0 = g * echunk;
  int e1 = e0 + echunk;
  if (e1 > E) e1 = E;
  if (e0 < e1) {
    if (is64 && ((E & 1) == 0)) {
      const int* w32 = (const int*)ei;
      int evend = e0 + ((e1 - e0) & ~1);
      for (int e = e0 + 2 * t; e + 1 < evend + 2; e += 512) {
        if (e + 1 >= e1) break;
        int4 d4 = *(const int4*)(w32 + 2 * ((size_t)E + e));
        atomicAdd(&lh[(unsigned)d4.x >> 6], 1);
        atomicAdd(&lh[(unsigned)d4.z >> 6], 1);
      }
      for (int e = evend + t; e < e1; e += 256)
        atomicAdd(&lh[(unsigned)load_dst(ei, 1, e, E) >> 6], 1);
    } else {
      for (int e = e0 + t; e < e1; e += 256)
        atomicAdd(&lh[(unsigned)load_dst(ei, is64, e, E) >> 6], 1);
    }
  }
  __syncthreads();
  int repl = g & (REPL - 1);
  for (int i = t; i < NBK; i += 256) {
    int v = lh[i];
    if (v) atomicAdd(&hist[i * REPL + repl], v);
  }
}

extern "C" __global__ __launch_bounds__(1024) void k_scanb(const int* __restrict__ hist,
                                                           int* __restrict__ boffs,
                                                           int* __restrict__ bcur, int M) {
  __shared__ int sh[1024];
  int tid = threadIdx.x;
  int C = (M + 1023) / 1024;
  int base = tid * C;
  int s = 0;
  for (int k = 0; k < C; k++) {
    int idx = base + k;
    if (idx < M) s += hist[idx];
  }
  sh[tid] = s;
  __syncthreads();
  for (int d = 1; d < 1024; d <<= 1) {
    int t2 = (tid >= d) ? sh[tid - d] : 0;
    __syncthreads();
    sh[tid] += t2;
    __syncthreads();
  }
  int run = sh[tid] - s;
  for (int k = 0; k < C; k++) {
    int idx = base + k;
    if (idx < M) {
      int v = hist[idx];
      boffs[idx] = run;
      bcur[idx] = run;
      run += v;
    }
  }
  if (tid == 1023) boffs[M] = run;  // == E
}

// scatter packed words src | (local_col<<20); same chunking as k_hist.
extern "C" __global__ __launch_bounds__(256) void k_bucket(const void* __restrict__ ei, int E,
                                                           int echunk, int* __restrict__ bcur,
                                                           unsigned int* __restrict__ bked,
                                                           const int* __restrict__ flag) {
  int g = blockIdx.x, t = threadIdx.x;
  int is64 = *flag;
  int repl = g & (REPL - 1);
  int e0 = g * echunk;
  int e1 = e0 + echunk;
  if (e1 > E) e1 = E;
  if (e0 >= e1) return;
  if (is64 && ((E & 1) == 0)) {
    const int* w32 = (const int*)ei;
    int evend = e0 + ((e1 - e0) & ~1);
    for (int e = e0 + 2 * t; e + 1 < evend + 2; e += 512) {
      if (e + 1 >= e1) break;
      int4 s4 = *(const int4*)(w32 + 2 * (size_t)e);
      int4 d4 = *(const int4*)(w32 + 2 * ((size_t)E + e));
      {
        int idx = ((unsigned)d4.x >> 6) * REPL + repl;
        int p = atomicAdd(&bcur[idx], 1);
        __builtin_nontemporal_store(
            (unsigned)s4.x | ((unsigned)(d4.x & (BTGT - 1)) << 20), &bked[p]);
      }
      {
        int idx = ((unsigned)d4.z >> 6) * REPL + repl;
        int p = atomicAdd(&bcur[idx], 1);
        __builtin_nontemporal_store(
            (unsigned)s4.z | ((unsigned)(d4.z & (BTGT - 1)) << 20), &bked[p]);
      }
    }
    for (int e = evend + t; e < e1; e += 256) {
      int r = load_src(ei, 1, e);
      int c = load_dst(ei, 1, e, E);
      int idx = ((unsigned)c >> 6) * REPL + repl;
      int p = atomicAdd(&bcur[idx], 1);
      __builtin_nontemporal_store(
          (unsigned)r | ((unsigned)(c & (BTGT - 1)) << 20), &bked[p]);
    }
  } else {
    for (int e = e0 + t; e < e1; e += 256) {
      int r = load_src(ei, is64, e);
      int c = load_dst(ei, is64, e, E);
      int idx = ((unsigned)c >> 6) * REPL + repl;
      int p = atomicAdd(&bcur[idx], 1);
      __builtin_nontemporal_store(
          (unsigned)r | ((unsigned)(c & (BTGT - 1)) << 20), &bked[p]);
    }
  }
}

// per-bucket local degree count -> dis = rsqrt(deg+1)
extern "C" __global__ __launch_bounds__(256) void k_degb(
    const unsigned int* __restrict__ bked, const int* __restrict__ boffs,
    float* __restrict__ dis, int n) {
  __shared__ int lc[BTGT];
  int b = blockIdx.x, t = threadIdx.x;
  if (t < BTGT) lc[t] = 0;
  __syncthreads();
  int beg = boffs[b * REPL], end = boffs[(b + 1) * REPL];
  for (int p = beg + t; p < end; p += 256) atomicAdd(&lc[bked[p] >> 20], 1);
  __syncthreads();
  if (t < BTGT) {
    int i = b * BTGT + t;
    if (i < n) dis[i] = rsqrtf((float)lc[t] + 1.0f);
  }
}

// hs(bf16) = dis .* (x @ W1). Block=256 rows, LDS-staged swizzled x tile.
extern "C" __global__ __launch_bounds__(256) void k_mm1s(
    const float* __restrict__ x, const float* __restrict__ W1, const float* __restrict__ dis,
    ushortT* __restrict__ hs, int n) {
  __shared__ float xs[256 * 32];
  __shared__ float w1s[F_IN * HDIM];
  int t = threadIdx.x;
  int row0 = blockIdx.x * 256;
  {
    const float4* wg = (const float4*)W1;
    float4* wl = (float4*)w1s;
    for (int i = t; i < F_IN * HDIM / 4; i += 256) wl[i] = wg[i];
  }
  int r = row0 + t;
  bool active = (r < n);
  bool fullblk = (row0 + 255 < n);
  float acc[HDIM];
#pragma unroll
  for (int j = 0; j < HDIM; j++) acc[j] = 0.f;

  float4* xs4 = (float4*)xs;
  for (int kc = 0; kc < F_IN / 32; kc++) {
    __syncthreads();
    if (fullblk) {
#pragma unroll
      for (int it = 0; it < 8; it++) {
        int f = it * 256 + t;
        int r2 = f >> 3, fi = f & 7;
        float4 v = ((const float4*)(x + (size_t)(row0 + r2) * F_IN + kc * 32))[fi];
        xs4[r2 * 8 + (fi ^ (r2 & 7))] = v;
      }
    } else {
      for (int it = 0; it < 8; it++) {
        int f = it * 256 + t;
        int r2 = f >> 3, fi = f & 7;
        float4 v = make_float4(0.f, 0.f, 0.f, 0.f);
        if (row0 + r2 < n)
          v = ((const float4*)(x + (size_t)(row0 + r2) * F_IN + kc * 32))[fi];
        xs4[r2 * 8 + (fi ^ (r2 & 7))] = v;
      }
    }
    __syncthreads();
    if (active) {
#pragma unroll
      for (int i = 0; i < 8; i++) {
        int ii = i ^ (t & 7);
        float4 xv = xs4[t * 8 + ii];
        float xk[4] = {xv.x, xv.y, xv.z, xv.w};
        int kb = kc * 32 + i * 4;
#pragma unroll
        for (int kk = 0; kk < 4; kk++) {
          const float4* wr = (const float4*)(w1s + (size_t)(kb + kk) * HDIM);
#pragma unroll
          for (int q = 0; q < HDIM / 4; q++) {
            float4 wv = wr[q];
            acc[4 * q + 0] = fmaf(xk[kk], wv.x, acc[4 * q + 0]);
            acc[4 * q + 1] = fmaf(xk[kk], wv.y, acc[4 * q + 1]);
            acc[4 * q + 2] = fmaf(xk[kk], wv.z, acc[4 * q + 2]);
            acc[4 * q + 3] = fmaf(xk[kk], wv.w, acc[4 * q + 3]);
          }
        }
      }
    }
  }
  if (active) {
    float d = dis[r];
    unsigned wds[8];
#pragma unroll
    for (int q = 0; q < 8; q++) {
      unsigned lo = f2bf(d * acc[2 * q]);
      unsigned hi = f2bf(d * acc[2 * q + 1]);
      wds[q] = lo | (hi << 16);
    }
    uint4* o = (uint4*)(hs + (size_t)r * HDIM);
    o[0] = make_uint4(wds[0], wds[1], wds[2], wds[3]);
    o[1] = make_uint4(wds[4], wds[5], wds[6], wds[7]);
  }
}

// One-lane-per-edge gather+accumulate. Lane loads its edge's full 32B bf16 row
// (2x uint4, one cache line) -> 64 independent lines in flight per wave instr.
// acc layout is per-row rotated: feature j of row lc lives at slot
// lc*16 + ((j+lc)&15)  -> LDS atomic banks spread ~2-way, j stays compile-time.
__device__ __forceinline__ void edge_accum(const ushortT* __restrict__ feat,
                                           float* __restrict__ acc, unsigned u) {
  unsigned src = u & 0xFFFFFu;
  int lc = (int)(u >> 20);
  int base = lc << 4;
  const uint4* rp = (const uint4*)(feat + ((size_t)src << 4));
  uint4 q0 = rp[0];
  uint4 q1 = rp[1];
  float f[16];
  f[0] = bf2f_lo(q0.x);  f[1] = bf2f_hi(q0.x);
  f[2] = bf2f_lo(q0.y);  f[3] = bf2f_hi(q0.y);
  f[4] = bf2f_lo(q0.z);  f[5] = bf2f_hi(q0.z);
  f[6] = bf2f_lo(q0.w);  f[7] = bf2f_hi(q0.w);
  f[8] = bf2f_lo(q1.x);  f[9] = bf2f_hi(q1.x);
  f[10] = bf2f_lo(q1.y); f[11] = bf2f_hi(q1.y);
  f[12] = bf2f_lo(q1.z); f[13] = bf2f_hi(q1.z);
  f[14] = bf2f_lo(q1.w); f[15] = bf2f_hi(q1.w);
#pragma unroll
  for (int j = 0; j < 16; j++) atomicAdd(&acc[base + ((j + lc) & 15)], f[j]);
}

__device__ __forceinline__ void agg_body(const ushortT* __restrict__ feat,
                                         const unsigned int* __restrict__ bked,
                                         float* __restrict__ acc, int beg, int end, int t) {
  int p = beg + t;
  // 2-edge manual unroll: 4 independent uint4 gathers in flight per lane.
  for (; p + 256 < end; p += 512) {
    unsigned u0 = __builtin_nontemporal_load(&bked[p]);
    unsigned u1 = __builtin_nontemporal_load(&bked[p + 256]);
    edge_accum(feat, acc, u0);
    edge_accum(feat, acc, u1);
  }
  if (p < end) {
    unsigned u = __builtin_nontemporal_load(&bked[p]);
    edge_accum(feat, acc, u);
  }
}

// layer-1 aggregate: zs(bf16) = dis * relu( di*(sum_nb hs[s] + hs[i]) + b1 )
extern "C" __global__ __launch_bounds__(256) void k_agg1(
    const ushortT* __restrict__ hs, const unsigned int* __restrict__ bked,
    const int* __restrict__ boffs, const float* __restrict__ dis,
    const float* __restrict__ b1, ushortT* __restrict__ zs, int n) {
  __shared__ float acc[BTGT * HDIM];
  int b = blockIdx.x, t = threadIdx.x;
  for (int k = t; k < BTGT * HDIM; k += 256) acc[k] = 0.f;
  __syncthreads();
  int beg = boffs[b * REPL], end = boffs[(b + 1) * REPL];
  agg_body(hs, bked, acc, beg, end, t);
  __syncthreads();
  int g = t >> 4, j = t & 15;
  for (int il = g; il < BTGT; il += 16) {
    int i = b * BTGT + il;
    if (i < n) {
      float di = dis[i];
      float a = acc[(il << 4) + ((j + il) & 15)];  // rotated slot for feature j
      float v = di * (a + bf2f(hs[(size_t)i * HDIM + j])) + b1[j];
      v = fmaxf(v, 0.f);
      zs[(size_t)i * HDIM + j] = (ushortT)f2bf(di * v);
    }
  }
}

// layer-2 aggregate fused with mm2: out = (di*(sum_nb zs[s] + zs[i])) @ W2 + b2
extern "C" __global__ __launch_bounds__(256) void k_agg2f(
    const ushortT* __restrict__ zs, const unsigned int* __restrict__ bked,
    const int* __restrict__ boffs, const float* __restrict__ dis,
    const float* __restrict__ W2, const float* __restrict__ b2, float* __restrict__ out,
    int n) {
  __shared__ float acc[BTGT * HDIM];
  __shared__ float w2s[HDIM * F_OUT];
  __shared__ float b2s[F_OUT];
  int b = blockIdx.x, t = threadIdx.x;
  for (int k = t; k < BTGT * HDIM; k += 256) acc[k] = 0.f;
  for (int k = t; k < HDIM * F_OUT; k += 256) w2s[k] = W2[k];
  if (t < F_OUT) b2s[t] = b2[t];
  __syncthreads();
  int beg = boffs[b * REPL], end = boffs[(b + 1) * REPL];
  agg_body(zs, bked, acc, beg, end, t);
  __syncthreads();
  int g = t >> 4, j = t & 15;
  for (int il = g; il < BTGT; il += 16) {
    int i = b * BTGT + il;
    if (i < n) {
      float di = dis[i];
      int s = (il << 4) + ((j + il) & 15);  // rotated slot for feature j
      acc[s] = di * (acc[s] + bf2f(zs[(size_t)i * HDIM + j]));
    }
  }
  __syncthreads();
  int il = t >> 2, qo = t & 3;
  int i = b * BTGT + il;
  if (i < n) {
    float tv[HDIM];
#pragma unroll
    for (int k = 0; k < HDIM; k++) tv[k] = acc[(il << 4) + ((k + il) & 15)];
#pragma unroll
    for (int jj = 0; jj < 10; jj++) {
      int col = qo * 10 + jj;
      float s = b2s[col];
#pragma unroll
      for (int k = 0; k < HDIM; k++) s = fmaf(tv[k], w2s[k * F_OUT + col], s);
      out[(size_t)i * F_OUT + col] = s;
    }
  }
}

extern "C" void kernel_launch(void* const* d_in, const int* in_sizes, int n_in,
                              void* d_out, int out_size, void* d_ws, size_t ws_size,
                              hipStream_t stream) {
  const float* x = (const float*)d_in[0];
  const void* ei = d_in[1];
  const float* W1 = (const float*)d_in[2];
  const float* b1 = (const float*)d_in[3];
  const float* W2 = (const float*)d_in[4];
  const float* b2 = (const float*)d_in[5];
  float* out = (float*)d_out;

  const int n = in_sizes[0] / F_IN;  // 100000
  const int E = in_sizes[1] / 2;     // 3200000
  const int NBK = (n + BTGT - 1) / BTGT;  // 1563
  const int M = NBK * REPL;               // 12504
  int echunk = (E + NCH - 1) / NCH;
  echunk = (echunk + 1) & ~1;  // even so int4 paths stay aligned

  char* w = (char*)d_ws;
  auto alloc = [&](size_t bytes) {
    char* p = w;
    w += (bytes + 255) & ~(size_t)255;
    return p;
  };
  int* flag = (int*)alloc(4);
  int* hist = (int*)alloc((size_t)M * 4);
  int* boffs = (int*)alloc((size_t)(M + 1) * 4);
  int* bcur = (int*)alloc((size_t)M * 4);
  float* dis = (float*)alloc((size_t)n * 4);
  unsigned int* bked = (unsigned int*)alloc((size_t)E * 4);
  ushortT* hs = (ushortT*)alloc((size_t)n * HDIM * 2);
  ushortT* zs = (ushortT*)alloc((size_t)n * HDIM * 2);

  dim3 B(256);
  hipLaunchKernelGGL(k_init, dim3((M + 255) / 256), B, 0, stream, hist, M, flag);
  int npairs = 4096;
  if (npairs > E) npairs = E;
  hipLaunchKernelGGL(k_detect, dim3((npairs + 255) / 256), B, 0, stream,
                     (const unsigned int*)ei, npairs, flag);
  hipLaunchKernelGGL(k_hist, dim3(NCH), B, (size_t)NBK * 4, stream, ei, E, echunk, hist, NBK,
                     flag);
  hipLaunchKernelGGL(k_scanb, dim3(1), dim3(1024), 0, stream, hist, boffs, bcur, M);
  hipLaunchKernelGGL(k_bucket, dim3(NCH), B, 0, stream, ei, E, echunk, bcur, bked, flag);
  hipLaunchKernelGGL(k_degb, dim3(NBK), B, 0, stream, bked, boffs, dis, n);
  hipLaunchKernelGGL(k_mm1s, dim3((n + 255) / 256), B, 0, stream, x, W1, dis, hs, n);
  hipLaunchKernelGGL(k_agg1, dim3(NBK), B, 0, stream, hs, bked, boffs, dis, b1, zs, n);
  hipLaunchKernelGGL(k_agg2f, dim3(NBK), B, 0, stream, zs, bked, boffs, dis, W2, b2, out, n);
}